// Round 1
// baseline (607.067 us; speedup 1.0000x reference)
//
#include <hip/hip_runtime.h>

#define LN_EPS 1e-5f

// ---------------------------------------------------------------------------
// Kernel 1: per-row MLP head: x2 = relu(LN(relu(LN(feat*W1+b1))@W2+b2))
// 2 rows per 256-thread block (128 threads per row, LN over 128 = 2 waves).
// ---------------------------------------------------------------------------
__global__ __launch_bounds__(256) void k1_mlp(
    const float* __restrict__ feat,
    const float* __restrict__ W1, const float* __restrict__ b1,
    const float* __restrict__ g1, const float* __restrict__ be1,
    const float* __restrict__ W2, const float* __restrict__ b2,
    const float* __restrict__ g2, const float* __restrict__ be2,
    float* __restrict__ x2out)
{
    const int ty = threadIdx.x >> 7;   // row within block: 0..1
    const int j  = threadIdx.x & 127;  // feature index
    const int row = blockIdx.x * 2 + ty;

    __shared__ float sx1[2][128];
    __shared__ float sred[2][2][2];    // [rowInBlk][waveInRow][{sum,sumsq}]

    const float f = feat[row];
    float v = fmaf(f, W1[j], b1[j]);

    // --- LN #1 over 128 threads (2 waves) ---
    float s = v, q = v * v;
    #pragma unroll
    for (int off = 32; off > 0; off >>= 1) {
        s += __shfl_down(s, off);
        q += __shfl_down(q, off);
    }
    const int wir = j >> 6;
    if ((j & 63) == 0) { sred[ty][wir][0] = s; sred[ty][wir][1] = q; }
    __syncthreads();
    float sum = sred[ty][0][0] + sred[ty][1][0];
    float sq  = sred[ty][0][1] + sred[ty][1][1];
    float mu  = sum * (1.0f / 128.0f);
    float var = fmaf(-mu, mu, sq * (1.0f / 128.0f));
    float x1  = fmaf((v - mu) * rsqrtf(var + LN_EPS), g1[j], be1[j]);
    x1 = fmaxf(x1, 0.0f);
    sx1[ty][j] = x1;
    __syncthreads();

    // --- x1 @ W2 + b2 (W2 coalesced over j, x1 LDS-broadcast) ---
    float a = b2[j];
    #pragma unroll 8
    for (int k = 0; k < 128; ++k)
        a = fmaf(sx1[ty][k], W2[k * 128 + j], a);

    // --- LN #2 ---
    s = a; q = a * a;
    #pragma unroll
    for (int off = 32; off > 0; off >>= 1) {
        s += __shfl_down(s, off);
        q += __shfl_down(q, off);
    }
    if ((j & 63) == 0) { sred[ty][wir][0] = s; sred[ty][wir][1] = q; }
    __syncthreads();
    sum = sred[ty][0][0] + sred[ty][1][0];
    sq  = sred[ty][0][1] + sred[ty][1][1];
    mu  = sum * (1.0f / 128.0f);
    var = fmaf(-mu, mu, sq * (1.0f / 128.0f));
    float x2v = fmaf((a - mu) * rsqrtf(var + LN_EPS), g2[j], be2[j]);
    x2v = fmaxf(x2v, 0.0f);
    x2out[row * 128 + j] = x2v;
}

// ---------------------------------------------------------------------------
// Kernel 2: fused Y = X2 @ W3 + b3 with einsum('oif,dmf->odim') epilogue.
// Block tile: 32 rows x 640 y-cols (=128 (o,i) pairs). 256 threads:
// tx (0..31) owns 4 pairs (20 y-cols), ty (0..7) owns 4 rows.
// Per-thread: acc[4 rows][20 cols] fp32. x2 transposed in LDS ([k][r], pad 36
// -> ds_read_b128, conflict-free). W3 read straight from L1/L2 (float4,
// addresses depend only on tx -> broadcast across ty). Basis staged in LDS.
// ---------------------------------------------------------------------------
__global__ __launch_bounds__(256) void k2_gemm_einsum(
    const float* __restrict__ x2,
    const float* __restrict__ W3, const float* __restrict__ b3,
    const float* __restrict__ basis,
    float* __restrict__ out)
{
    const int tid = threadIdx.x;
    const int tx  = tid & 31;
    const int ty  = tid >> 5;
    const int row0 = blockIdx.x * 32;   // 128 row-blocks (x fastest: co-resident
    const int p0   = blockIdx.y * 128;  //  blocks share the same W3 slab in L1/L2)

    __shared__ float sX[128][36];       // x2 transposed [k][r], +4 pad
    __shared__ float sB[32 * 125];      // basis rows, compact

    // stage x2 transposed: thread -> row r = tid>>3, k-chunk of 16
    {
        const int r  = tid >> 3;
        const int k0 = (tid & 7) * 16;
        const float4* src = (const float4*)(x2 + (size_t)(row0 + r) * 128 + k0);
        #pragma unroll
        for (int jj = 0; jj < 4; ++jj) {
            float4 vv = src[jj];
            sX[k0 + jj * 4 + 0][r] = vv.x;
            sX[k0 + jj * 4 + 1][r] = vv.y;
            sX[k0 + jj * 4 + 2][r] = vv.z;
            sX[k0 + jj * 4 + 3][r] = vv.w;
        }
    }
    // stage basis (32 rows x 125 contiguous floats)
    for (int idx = tid; idx < 32 * 125; idx += 256)
        sB[idx] = basis[(size_t)row0 * 125 + idx];
    __syncthreads();

    // init accumulators with b3 (y = x2@W3 + b3)
    float acc[4][20];
    {
        const float4* bp = (const float4*)(b3 + p0 * 5 + tx * 20);
        float4 q0 = bp[0], q1 = bp[1], q2 = bp[2], q3 = bp[3], q4 = bp[4];
        const float bb[20] = {q0.x, q0.y, q0.z, q0.w, q1.x, q1.y, q1.z, q1.w,
                              q2.x, q2.y, q2.z, q2.w, q3.x, q3.y, q3.z, q3.w,
                              q4.x, q4.y, q4.z, q4.w};
        #pragma unroll
        for (int r = 0; r < 4; ++r)
            #pragma unroll
            for (int c = 0; c < 20; ++c)
                acc[r][c] = bb[c];
    }

    // K-loop: 128 iterations, 80 FMAs each
    const float* w3p = W3 + p0 * 5 + tx * 20;
    #pragma unroll 2
    for (int k = 0; k < 128; ++k) {
        const float4* wr = (const float4*)(w3p + (size_t)k * 5120);
        float4 w0 = wr[0], w1 = wr[1], w2 = wr[2], w3v = wr[3], w4 = wr[4];
        const float wc[20] = {w0.x, w0.y, w0.z, w0.w, w1.x, w1.y, w1.z, w1.w,
                              w2.x, w2.y, w2.z, w2.w, w3v.x, w3v.y, w3v.z, w3v.w,
                              w4.x, w4.y, w4.z, w4.w};
        const float4 xv = *(const float4*)&sX[k][ty * 4];
        const float xs[4] = {xv.x, xv.y, xv.z, xv.w};
        #pragma unroll
        for (int r = 0; r < 4; ++r)
            #pragma unroll
            for (int c = 0; c < 20; ++c)
                acc[r][c] = fmaf(xs[r], wc[c], acc[r][c]);
    }

    // einsum epilogue: out[row, o*5+d, i*5+m] = sum_f R[o,i,f] * B[d,m,f]
    const int pb = p0 + tx * 4;   // first pair of this thread
    const int o  = pb >> 5;       // same o for all 4 pairs (pb aligned to 4)
    const int i0 = pb & 31;

    #pragma unroll
    for (int rs = 0; rs < 4; ++rs) {
        const int rl = ty * 4 + rs;
        float* orow = out + (size_t)(row0 + rl) * 25600 + (size_t)o * 800 + i0 * 5;
        const float* Br = sB + rl * 125;
        #pragma unroll
        for (int d = 0; d < 5; ++d) {
            float Bv[25];
            #pragma unroll
            for (int qq = 0; qq < 25; ++qq) Bv[qq] = Br[d * 25 + qq];
            float vv[20];
            #pragma unroll
            for (int p = 0; p < 4; ++p) {
                #pragma unroll
                for (int m = 0; m < 5; ++m) {
                    float t = acc[rs][p * 5 + 0] * Bv[m * 5 + 0];
                    t = fmaf(acc[rs][p * 5 + 1], Bv[m * 5 + 1], t);
                    t = fmaf(acc[rs][p * 5 + 2], Bv[m * 5 + 2], t);
                    t = fmaf(acc[rs][p * 5 + 3], Bv[m * 5 + 3], t);
                    t = fmaf(acc[rs][p * 5 + 4], Bv[m * 5 + 4], t);
                    vv[p * 5 + m] = t;
                }
            }
            float4* dst = (float4*)(orow + d * 160);  // 16B aligned (i0*5 % 4 == 0)
            dst[0] = make_float4(vv[0],  vv[1],  vv[2],  vv[3]);
            dst[1] = make_float4(vv[4],  vv[5],  vv[6],  vv[7]);
            dst[2] = make_float4(vv[8],  vv[9],  vv[10], vv[11]);
            dst[3] = make_float4(vv[12], vv[13], vv[14], vv[15]);
            dst[4] = make_float4(vv[16], vv[17], vv[18], vv[19]);
        }
    }
}

// ---------------------------------------------------------------------------
extern "C" void kernel_launch(void* const* d_in, const int* in_sizes, int n_in,
                              void* d_out, int out_size, void* d_ws, size_t ws_size,
                              hipStream_t stream)
{
    const float* feat  = (const float*)d_in[0];
    const float* basis = (const float*)d_in[1];
    const float* W1    = (const float*)d_in[2];
    const float* b1    = (const float*)d_in[3];
    const float* g1    = (const float*)d_in[4];
    const float* be1   = (const float*)d_in[5];
    const float* W2    = (const float*)d_in[6];
    const float* b2    = (const float*)d_in[7];
    const float* g2    = (const float*)d_in[8];
    const float* be2   = (const float*)d_in[9];
    const float* W3    = (const float*)d_in[10];
    const float* b3    = (const float*)d_in[11];

    float* out = (float*)d_out;
    float* x2  = (float*)d_ws;   // 4096*128 fp32 = 2 MB scratch

    const int rows = 4096;       // b*n*h = 2*64*32

    k1_mlp<<<rows / 2, 256, 0, stream>>>(feat, W1, b1, g1, be1, W2, b2, g2, be2, x2);

    dim3 grid(rows / 32, 8);     // 128 row-blocks x 8 col-blocks
    k2_gemm_einsum<<<grid, 256, 0, stream>>>(x2, W3, b3, basis, out);
}

// Round 2
// 560.655 us; speedup vs baseline: 1.0828x; 1.0828x over previous
//
#include <hip/hip_runtime.h>

#define LN_EPS 1e-5f

typedef __attribute__((ext_vector_type(8)))  short bf16x8;    // 8 bf16 = 4 VGPRs
typedef __attribute__((ext_vector_type(16))) float floatx16;  // MFMA 32x32 acc

static __device__ __forceinline__ unsigned short f2bf(float x) {
    union { float f; unsigned u; } v; v.f = x;
    unsigned r = v.u + 0x7FFFu + ((v.u >> 16) & 1u);   // round-to-nearest-even
    return (unsigned short)(r >> 16);
}

// ---------------------------------------------------------------------------
// Kernel 1: per-row MLP head: x2 = relu(LN(relu(LN(feat*W1+b1))@W2+b2))
// (unchanged from round 1 — verified correct)
// ---------------------------------------------------------------------------
__global__ __launch_bounds__(256) void k1_mlp(
    const float* __restrict__ feat,
    const float* __restrict__ W1, const float* __restrict__ b1,
    const float* __restrict__ g1, const float* __restrict__ be1,
    const float* __restrict__ W2, const float* __restrict__ b2,
    const float* __restrict__ g2, const float* __restrict__ be2,
    float* __restrict__ x2out)
{
    const int ty = threadIdx.x >> 7;
    const int j  = threadIdx.x & 127;
    const int row = blockIdx.x * 2 + ty;

    __shared__ float sx1[2][128];
    __shared__ float sred[2][2][2];

    const float f = feat[row];
    float v = fmaf(f, W1[j], b1[j]);

    float s = v, q = v * v;
    #pragma unroll
    for (int off = 32; off > 0; off >>= 1) {
        s += __shfl_down(s, off);
        q += __shfl_down(q, off);
    }
    const int wir = j >> 6;
    if ((j & 63) == 0) { sred[ty][wir][0] = s; sred[ty][wir][1] = q; }
    __syncthreads();
    float sum = sred[ty][0][0] + sred[ty][1][0];
    float sq  = sred[ty][0][1] + sred[ty][1][1];
    float mu  = sum * (1.0f / 128.0f);
    float var = fmaf(-mu, mu, sq * (1.0f / 128.0f));
    float x1  = fmaf((v - mu) * rsqrtf(var + LN_EPS), g1[j], be1[j]);
    x1 = fmaxf(x1, 0.0f);
    sx1[ty][j] = x1;
    __syncthreads();

    float a = b2[j];
    #pragma unroll 8
    for (int k = 0; k < 128; ++k)
        a = fmaf(sx1[ty][k], W2[k * 128 + j], a);

    s = a; q = a * a;
    #pragma unroll
    for (int off = 32; off > 0; off >>= 1) {
        s += __shfl_down(s, off);
        q += __shfl_down(q, off);
    }
    if ((j & 63) == 0) { sred[ty][wir][0] = s; sred[ty][wir][1] = q; }
    __syncthreads();
    sum = sred[ty][0][0] + sred[ty][1][0];
    sq  = sred[ty][0][1] + sred[ty][1][1];
    mu  = sum * (1.0f / 128.0f);
    var = fmaf(-mu, mu, sq * (1.0f / 128.0f));
    float x2v = fmaf((a - mu) * rsqrtf(var + LN_EPS), g2[j], be2[j]);
    x2v = fmaxf(x2v, 0.0f);
    x2out[row * 128 + j] = x2v;
}

// ---------------------------------------------------------------------------
// Repack x2 (fp32 [4096][128]) -> A-frag-ordered bf16 for mfma_32x32x16_bf16.
// A[m][k]: m = lane&31, k = (lane>>5)*8 + j.  Flat: ((R*8+s)*64+lane)*8+j,
// R = 32-row block, s = K16 step. One thread per (R,s,lane); 16B stores.
// ---------------------------------------------------------------------------
__global__ __launch_bounds__(256) void k_repack_x(
    const float* __restrict__ x2, unsigned int* __restrict__ A)
{
    const int g = blockIdx.x * 256 + threadIdx.x;   // 65536
    const int L = g & 63;
    const int s = (g >> 6) & 7;
    const int R = g >> 9;
    const int row = R * 32 + (L & 31);
    const int kb  = s * 16 + (L >> 5) * 8;
    const float4* src = (const float4*)(x2 + (size_t)row * 128 + kb);
    float4 a = src[0], b = src[1];
    uint4 w;
    w.x = f2bf(a.x) | ((unsigned)f2bf(a.y) << 16);
    w.y = f2bf(a.z) | ((unsigned)f2bf(a.w) << 16);
    w.z = f2bf(b.x) | ((unsigned)f2bf(b.y) << 16);
    w.w = f2bf(b.z) | ((unsigned)f2bf(b.w) << 16);
    ((uint4*)A)[g] = w;
}

// ---------------------------------------------------------------------------
// Repack W3 (fp32 [128][5120]) -> B-frag-ordered bf16.
// B[k][n]: n = lane&31, k = (lane>>5)*8 + j.  Flat: ((t*8+s)*64+lane)*8+j,
// t = 32-col tile (160 of them). Gather reads (L2-resident, one-time).
// ---------------------------------------------------------------------------
__global__ __launch_bounds__(256) void k_repack_w(
    const float* __restrict__ W3, unsigned int* __restrict__ B)
{
    const int g = blockIdx.x * 256 + threadIdx.x;   // 81920
    const int L = g & 63;
    const int s = (g >> 6) & 7;
    const int t = g >> 9;
    const int n  = t * 32 + (L & 31);
    const int kb = s * 16 + (L >> 5) * 8;
    unsigned short o[8];
    #pragma unroll
    for (int j = 0; j < 8; ++j)
        o[j] = f2bf(W3[(size_t)(kb + j) * 5120 + n]);
    uint4 w;
    w.x = o[0] | ((unsigned)o[1] << 16);
    w.y = o[2] | ((unsigned)o[3] << 16);
    w.z = o[4] | ((unsigned)o[5] << 16);
    w.w = o[6] | ((unsigned)o[7] << 16);
    ((uint4*)B)[g] = w;
}

// ---------------------------------------------------------------------------
// MFMA GEMM: Y = x2 @ W3 + b3  (4096x5120, K=128), bf16 in / fp32 out.
// Block = 32 rows x 640 cols, 4 waves; wave w owns 5 col-tiles of 32.
// Frag loads are contiguous dwordx4 from the repacked arrays (no LDS).
// C layout (verified m74/m101): col=lane&31, row=(reg&3)+8*(reg>>2)+4*(lane>>5).
// ---------------------------------------------------------------------------
__global__ __launch_bounds__(256) void k_gemm(
    const unsigned int* __restrict__ Abf, const unsigned int* __restrict__ Bbf,
    const float* __restrict__ b3, float* __restrict__ Y)
{
    const int lane = threadIdx.x & 63;
    const int w    = threadIdx.x >> 6;
    const int R    = blockIdx.x;            // 32-row block
    const int cb   = blockIdx.y;            // 640-col block
    const int t0   = cb * 20 + w * 5;       // first global col-tile

    floatx16 acc[5];
    #pragma unroll
    for (int tt = 0; tt < 5; ++tt) acc[tt] = (floatx16)0.0f;

    const uint4* Ap = (const uint4*)Abf + (size_t)R * 512 + lane;
    const uint4* Bp = (const uint4*)Bbf + (size_t)t0 * 512 + lane;

    #pragma unroll
    for (int s = 0; s < 8; ++s) {
        bf16x8 a = *(const bf16x8*)(Ap + s * 64);
        #pragma unroll
        for (int tt = 0; tt < 5; ++tt) {
            bf16x8 b = *(const bf16x8*)(Bp + (size_t)tt * 512 + s * 64);
            acc[tt] = __builtin_amdgcn_mfma_f32_32x32x16_bf16(a, b, acc[tt], 0, 0, 0);
        }
    }

    const int m_hi = 4 * (lane >> 5);
    const int nl   = lane & 31;
    float* yb = Y + (size_t)R * 32 * 5120;
    #pragma unroll
    for (int tt = 0; tt < 5; ++tt) {
        const int n = (t0 + tt) * 32 + nl;
        const float bias = b3[n];
        #pragma unroll
        for (int reg = 0; reg < 16; ++reg) {
            const int m = (reg & 3) + 8 * (reg >> 2) + m_hi;
            yb[(size_t)m * 5120 + n] = acc[tt][reg] + bias;
        }
    }
}

// ---------------------------------------------------------------------------
// Einsum epilogue kernel: out[row, o*5+d, i*5+m] = sum_f Y[row,(o,i),f]*B[d,m,f]
// Same structure as the verified round-1 epilogue; Y read from global (L3-hot).
// ---------------------------------------------------------------------------
__global__ __launch_bounds__(256) void k_einsum(
    const float* __restrict__ Y, const float* __restrict__ basis,
    float* __restrict__ out)
{
    const int tid = threadIdx.x;
    const int tx  = tid & 31;
    const int ty  = tid >> 5;
    const int row0 = blockIdx.x * 32;
    const int p0   = blockIdx.y * 128;

    __shared__ float sB[32 * 125];
    for (int idx = tid; idx < 32 * 125; idx += 256)
        sB[idx] = basis[(size_t)row0 * 125 + idx];
    __syncthreads();

    float acc[4][20];
    #pragma unroll
    for (int r = 0; r < 4; ++r) {
        const float4* yp = (const float4*)(Y + (size_t)(row0 + ty * 4 + r) * 5120
                                             + p0 * 5 + tx * 20);
        float4 q0 = yp[0], q1 = yp[1], q2 = yp[2], q3 = yp[3], q4 = yp[4];
        acc[r][0]=q0.x;  acc[r][1]=q0.y;  acc[r][2]=q0.z;  acc[r][3]=q0.w;
        acc[r][4]=q1.x;  acc[r][5]=q1.y;  acc[r][6]=q1.z;  acc[r][7]=q1.w;
        acc[r][8]=q2.x;  acc[r][9]=q2.y;  acc[r][10]=q2.z; acc[r][11]=q2.w;
        acc[r][12]=q3.x; acc[r][13]=q3.y; acc[r][14]=q3.z; acc[r][15]=q3.w;
        acc[r][16]=q4.x; acc[r][17]=q4.y; acc[r][18]=q4.z; acc[r][19]=q4.w;
    }

    const int pb = p0 + tx * 4;
    const int o  = pb >> 5;
    const int i0 = pb & 31;

    #pragma unroll
    for (int rs = 0; rs < 4; ++rs) {
        const int rl = ty * 4 + rs;
        float* orow = out + (size_t)(row0 + rl) * 25600 + (size_t)o * 800 + i0 * 5;
        const float* Br = sB + rl * 125;
        #pragma unroll
        for (int d = 0; d < 5; ++d) {
            float Bv[25];
            #pragma unroll
            for (int qq = 0; qq < 25; ++qq) Bv[qq] = Br[d * 25 + qq];
            float vv[20];
            #pragma unroll
            for (int p = 0; p < 4; ++p) {
                #pragma unroll
                for (int m = 0; m < 5; ++m) {
                    float t = acc[rs][p * 5 + 0] * Bv[m * 5 + 0];
                    t = fmaf(acc[rs][p * 5 + 1], Bv[m * 5 + 1], t);
                    t = fmaf(acc[rs][p * 5 + 2], Bv[m * 5 + 2], t);
                    t = fmaf(acc[rs][p * 5 + 3], Bv[m * 5 + 3], t);
                    t = fmaf(acc[rs][p * 5 + 4], Bv[m * 5 + 4], t);
                    vv[p * 5 + m] = t;
                }
            }
            float4* dst = (float4*)(orow + d * 160);
            dst[0] = make_float4(vv[0],  vv[1],  vv[2],  vv[3]);
            dst[1] = make_float4(vv[4],  vv[5],  vv[6],  vv[7]);
            dst[2] = make_float4(vv[8],  vv[9],  vv[10], vv[11]);
            dst[3] = make_float4(vv[12], vv[13], vv[14], vv[15]);
            dst[4] = make_float4(vv[16], vv[17], vv[18], vv[19]);
        }
    }
}

// ---------------------------------------------------------------------------
extern "C" void kernel_launch(void* const* d_in, const int* in_sizes, int n_in,
                              void* d_out, int out_size, void* d_ws, size_t ws_size,
                              hipStream_t stream)
{
    const float* feat  = (const float*)d_in[0];
    const float* basis = (const float*)d_in[1];
    const float* W1    = (const float*)d_in[2];
    const float* b1    = (const float*)d_in[3];
    const float* g1    = (const float*)d_in[4];
    const float* be1   = (const float*)d_in[5];
    const float* W2    = (const float*)d_in[6];
    const float* b2    = (const float*)d_in[7];
    const float* g2    = (const float*)d_in[8];
    const float* be2   = (const float*)d_in[9];
    const float* W3    = (const float*)d_in[10];
    const float* b3    = (const float*)d_in[11];

    float* out = (float*)d_out;

    // ws layout (bytes): x2 [0, 2M) | Abf [2M, 3M) | Bbf [3M, 4.25M) | Y [4.25M, 84.25M)
    char* ws = (char*)d_ws;
    float*        x2  = (float*)(ws);                         // 4096*128*4  = 2,097,152
    unsigned int* Abf = (unsigned int*)(ws + 2097152);        // 65536*16    = 1,048,576
    unsigned int* Bbf = (unsigned int*)(ws + 3145728);        // 81920*16    = 1,310,720
    float*        Yt  = (float*)(ws + 4456448);               // 4096*5120*4 = 83,886,080

    const int rows = 4096;   // b*n*h = 2*64*32

    k1_mlp<<<rows / 2, 256, 0, stream>>>(feat, W1, b1, g1, be1, W2, b2, g2, be2, x2);
    k_repack_x<<<256, 256, 0, stream>>>(x2, Abf);
    k_repack_w<<<320, 256, 0, stream>>>(W3, Bbf);

    dim3 ggrid(rows / 32, 8);
    k_gemm<<<ggrid, 256, 0, stream>>>(Abf, Bbf, b3, Yt);

    dim3 egrid(rows / 32, 8);
    k_einsum<<<egrid, 256, 0, stream>>>(Yt, basis, out);
}